// Round 6
// baseline (513.223 us; speedup 1.0000x reference)
//
#include <hip/hip_runtime.h>
#include <hip/hip_bf16.h>

#define B_DIM   16384
#define D_IN    1024
#define D_EXP   1024
#define D_TOW   512
#define N_EXPT  8
#define N_TASK  4

typedef _Float16 f16x8 __attribute__((ext_vector_type(8)));
typedef _Float16 f16x4 __attribute__((ext_vector_type(4)));
typedef float    f32x4 __attribute__((ext_vector_type(4)));

// ---------------- async global->LDS (16B per lane, wave-uniform LDS base) ---
__device__ __forceinline__ void gll16(const void* g, void* l) {
  __builtin_amdgcn_global_load_lds(
      (const __attribute__((address_space(1))) unsigned int*)g,
      (__attribute__((address_space(3))) unsigned int*)l,
      16, 0, 0);
}

// Fragment read from a swizzled [128][64] f16 LDS half-tile.
// 16B chunk s within a 128B row holds global chunk s^(row&7).
__device__ __forceinline__ f16x8 ldfrag(const _Float16* sM, int rowbase, int ks, int lane) {
  int rl = rowbase + (lane & 15);
  int ch = ((ks << 2) + (lane >> 4)) ^ (rl & 7);
  return *(const f16x8*)&sM[rl * 64 + ch * 8];
}

// ---------------- prep: x -> f16, gates = x @ gate_w (fp32) ----------------
__global__ __launch_bounds__(256) void prep_x_kernel(
    const float* __restrict__ x, const float* __restrict__ gw,
    _Float16* __restrict__ xh, float* __restrict__ gates)
{
  __shared__ float sred[4][8];
  const int t = threadIdx.x;
  const long row = blockIdx.x;
  float4 v = ((const float4*)(x + row * D_IN))[t];
  f16x4 h;
  h[0] = (_Float16)v.x; h[1] = (_Float16)v.y; h[2] = (_Float16)v.z; h[3] = (_Float16)v.w;
  ((f16x4*)(xh + row * D_IN))[t] = h;

  float g[8];
#pragma unroll
  for (int e = 0; e < 8; ++e) g[e] = 0.f;
  const float* wp = gw + (size_t)t * 4 * 8;
  float xs[4] = {v.x, v.y, v.z, v.w};
#pragma unroll
  for (int j = 0; j < 4; ++j)
#pragma unroll
    for (int e = 0; e < 8; ++e) g[e] += xs[j] * wp[j * 8 + e];

#pragma unroll
  for (int e = 0; e < 8; ++e) {
    g[e] += __shfl_xor(g[e], 1);  g[e] += __shfl_xor(g[e], 2);
    g[e] += __shfl_xor(g[e], 4);  g[e] += __shfl_xor(g[e], 8);
    g[e] += __shfl_xor(g[e], 16); g[e] += __shfl_xor(g[e], 32);
  }
  if ((t & 63) == 0) {
#pragma unroll
    for (int e = 0; e < 8; ++e) sred[t >> 6][e] = g[e];
  }
  __syncthreads();
  if (t < 8) gates[row * 8 + t] = sred[0][t] + sred[1][t] + sred[2][t] + sred[3][t];
}

// ---------------- tiled transpose + fp32->f16: in[s][K][N] -> out[s][N][K] --
__global__ __launch_bounds__(256) void transpose_cvt_kernel(
    const float* __restrict__ in, _Float16* __restrict__ outp, int K, int N)
{
  __shared__ float tile[64][65];
  const int t = threadIdx.x;
  const int tx = t & 63, ty = t >> 6;
  const int n0 = blockIdx.x * 64;
  const int k0 = blockIdx.y * 64;
  const long s = blockIdx.z;
  const float* ip = in + s * (long)K * N;
  _Float16* op = outp + s * (long)K * N;
#pragma unroll
  for (int i = 0; i < 16; ++i) {
    int r = ty * 16 + i;
    tile[r][tx] = ip[(long)(k0 + r) * N + n0 + tx];
  }
  __syncthreads();
#pragma unroll
  for (int i = 0; i < 16; ++i) {
    int r = ty * 16 + i;
    op[(long)(n0 + r) * K + k0 + tx] = (_Float16)tile[tx][r];
  }
}

// ---------------- init d_out with tb2 --------------------------------------
__global__ void init_out_kernel(float* __restrict__ out, const float* __restrict__ tb2) {
  int i = blockIdx.x * 256 + threadIdx.x;
  if (i < N_TASK * B_DIM) out[i] = tb2[i >> 14];
}

// ============ K-tile body: pipelined fragment reads + 64 MFMA ===============
// BM=256, BN=256, BK=64; 8 waves 2M x 4N; per-wave C = 128x64.
// Register pipeline: af ping-pong one quadrant ahead; bf split in two pairs.
#define LOADA(DST, Q)                                                          \
    _Pragma("unroll") for (int m2 = 0; m2 < 2; ++m2)                           \
      _Pragma("unroll") for (int ks = 0; ks < 2; ++ks)                         \
        DST[m2][ks] = ldfrag(sA, ((Q) * 2 + m2) * 16, ks, lane)

#define LOADB(NF0)                                                             \
    _Pragma("unroll") for (int nf = (NF0); nf < (NF0) + 2; ++nf)               \
      _Pragma("unroll") for (int ks = 0; ks < 2; ++ks)                         \
        bf[nf][ks] = ldfrag(sB, (wn & 1) * 64 + nf * 16, ks, lane)

#define MFMA8(Q, AF)                                                           \
    _Pragma("unroll") for (int nf = 0; nf < 4; ++nf)                           \
      _Pragma("unroll") for (int m2 = 0; m2 < 2; ++m2)                         \
        _Pragma("unroll") for (int ks = 0; ks < 2; ++ks)                       \
          acc[(Q) * 2 + m2][nf] = __builtin_amdgcn_mfma_f32_16x16x32_f16(      \
              AF[m2][ks], bf[nf][ks], acc[(Q) * 2 + m2][nf], 0, 0, 0)

#define KTILE_COMPUTE(CUR)                                                     \
  do {                                                                         \
    const _Float16* sA = &sT[CUR][wm * 8192];                                  \
    const _Float16* sB = &sT[CUR][16384 + (wn >> 1) * 8192];                   \
    f16x8 af0[2][2], af1[2][2], bf[4][2];                                      \
    LOADA(af0, 0); LOADB(0);                                                   \
    LOADA(af1, 1); LOADB(2);                                                   \
    __builtin_amdgcn_s_setprio(1); MFMA8(0, af0);                              \
    __builtin_amdgcn_s_setprio(0);                                             \
    LOADA(af0, 2);                                                             \
    __builtin_amdgcn_s_setprio(1); MFMA8(1, af1);                              \
    __builtin_amdgcn_s_setprio(0);                                             \
    LOADA(af1, 3);                                                             \
    __builtin_amdgcn_s_setprio(1); MFMA8(2, af0); MFMA8(3, af1);               \
    __builtin_amdgcn_s_setprio(0);                                             \
  } while (0)

#define FENCE asm volatile("" ::: "memory")

// ---------------- fused experts + gate-weighted combine ---------------------
// shared[b,d] = sum_e gates[b,e] * relu(x[b,:] @ exp_w[e,:,d] + exp_b[e,d])
__global__ __launch_bounds__(512, 2) void moe_expert_kernel(
    const _Float16* __restrict__ xh,    // [B,1024]
    const _Float16* __restrict__ ewT,   // [8][n=1024][k=1024]
    const float* __restrict__ expb,     // [8][1024]
    const float* __restrict__ gates,    // [B][8]
    _Float16* __restrict__ shout)       // [B,1024] f16
{
  __shared__ alignas(16) _Float16 sT[2][32768];   // 128KB
  __shared__ float sG[256 * 8];                   // 8KB
  __shared__ _Float16 sBiasH[8 * 256];            // 4KB
  const int t = threadIdx.x;
  const int lane = t & 63;
  const int wave = t >> 6;
  const int wm = wave >> 2, wn = wave & 3;

  // bx-fastest: 64 consecutive blocks share one 4MB B-panel (fits XCD L2)
  const int h = blockIdx.x;                 // 256 blocks
  const int bx = h & 63;
  const int by = h >> 6;
  const long row0 = (long)bx * 256;
  const int col0 = by * 256;

  for (int i = t; i < 256 * 8; i += 512) sG[i] = gates[row0 * 8 + i];
  for (int i = t; i < 8 * 256; i += 512)
    sBiasH[i] = (_Float16)expb[(i >> 8) * D_EXP + col0 + (i & 255)];

  const int so_t = (((t & 7) ^ ((t >> 3) & 7)) << 4);
  const char* aBase = (const char*)xh + row0 * 2048 + (size_t)(t >> 3) * 2048 + so_t;
  const char* bRoot = (const char*)ewT + (size_t)col0 * 2048 + (size_t)(t >> 3) * 2048 + so_t;
  char* sTB = (char*)&sT[0][0];

  auto SA = [&](int s, int hh, int kt) {
    const char* g = aBase + (size_t)hh * 262144 + (size_t)(kt & 15) * 128;
    char* d = sTB + s * 65536 + hh * 16384 + t * 16;
    gll16(g, d); gll16(g + 131072, d + 8192);
    FENCE;
  };
  auto SB = [&](int s, int hh, int kt) {
    const char* g = bRoot + (size_t)(kt >> 4) * 2097152 + (size_t)hh * 262144
                    + (size_t)(kt & 15) * 128;
    char* d = sTB + s * 65536 + 32768 + hh * 16384 + t * 16;
    gll16(g, d); gll16(g + 131072, d + 8192);
    FENCE;
  };

  __syncthreads();   // sG/sBias visible; vmcnt fully drained -> clean FIFO

  // prologue: kt0 -> slot0 (8 loads), kt1 -> slot1 (8 loads)
  SA(0, 0, 0); SA(0, 1, 0); SB(0, 0, 0); SB(0, 1, 0);
  SA(1, 0, 1); SA(1, 1, 1); SB(1, 0, 1); SB(1, 1, 1);
  asm volatile("s_waitcnt vmcnt(8)" ::: "memory");
  __builtin_amdgcn_s_barrier();
  FENCE;

  f32x4 acc[8][4] = {};
  f16x4 shacc[8][4] = {};

  for (int kt = 0; kt < 128; ++kt) {
    const int cur = kt & 1;

    KTILE_COMPUTE(cur);

    FENCE;
    __builtin_amdgcn_s_barrier();   // all waves done reading slot cur
    FENCE;

    if (kt < 126) {                 // stage kt+2 into slot cur (now safe)
      SA(cur, 0, kt + 2); SA(cur, 1, kt + 2);
      SB(cur, 0, kt + 2); SB(cur, 1, kt + 2);
    }

    if ((kt & 15) == 15) {          // expert boundary: relu+bias+gate combine
      const int e = kt >> 4;
      float bias4[4];
#pragma unroll
      for (int nf = 0; nf < 4; ++nf)
        bias4[nf] = (float)sBiasH[e * 256 + wn * 64 + nf * 16 + (lane & 15)];
#pragma unroll
      for (int mf = 0; mf < 8; ++mf) {
        int rbase = wm * 128 + mf * 16 + ((lane >> 4) << 2);
        float gv[4];
#pragma unroll
        for (int r = 0; r < 4; ++r) gv[r] = sG[(rbase + r) * 8 + e];
#pragma unroll
        for (int nf = 0; nf < 4; ++nf) {
          f16x4 sh = shacc[mf][nf];
#pragma unroll
          for (int r = 0; r < 4; ++r) {
            float hv = acc[mf][nf][r] + bias4[nf];
            hv = hv > 0.f ? hv : 0.f;
            sh[r] += (_Float16)(gv[r] * hv);
          }
          shacc[mf][nf] = sh;
          acc[mf][nf] = f32x4{0.f, 0.f, 0.f, 0.f};
        }
      }
    }

    if (kt < 127) {                 // wait for next slot's data, re-sync
      if (kt < 126) { asm volatile("s_waitcnt vmcnt(8)" ::: "memory"); }
      else          { asm volatile("s_waitcnt vmcnt(0)" ::: "memory"); }
      __builtin_amdgcn_s_barrier();
      FENCE;
    }
  }

  // write shared tile as f16
#pragma unroll
  for (int mf = 0; mf < 8; ++mf)
#pragma unroll
    for (int r = 0; r < 4; ++r) {
      long row = row0 + wm * 128 + mf * 16 + ((lane >> 4) << 2) + r;
      _Float16* op = shout + row * D_EXP + col0 + wn * 64 + (lane & 15);
#pragma unroll
      for (int nf = 0; nf < 4; ++nf) op[nf * 16] = shacc[mf][nf][r];
    }
}

// ---------------- fused towers ----------------------------------------------
// out[task,b] += sum_h relu(shared[b,:] @ tw1[task,:,h] + tb1[task,h]) * tw2[task,h]
__global__ __launch_bounds__(512, 2) void moe_tower_kernel(
    const _Float16* __restrict__ sh,    // [B,1024] f16
    const _Float16* __restrict__ t1T,   // [4][h=512][d=1024] f16
    const float* __restrict__ tb1,      // [4][512]
    const float* __restrict__ tw2,      // [4][512]
    float* __restrict__ out)            // [4][B]
{
  __shared__ alignas(16) _Float16 sT[2][32768];   // 128KB
  const int t = threadIdx.x;
  const int lane = t & 63;
  const int wave = t >> 6;
  const int wm = wave >> 2, wn = wave & 3;

  // by-fastest: 8 consecutive blocks share the A-panel; B unique 4MB total
  const int h = blockIdx.x;                 // 512 blocks
  const int by = h & 7;                     // 0..7
  const int bx = h >> 3;                    // 0..63
  const long row0 = (long)bx * 256;
  const int task = by >> 1;
  const int col0 = (by & 1) * 256;

  float b1[4], w2[4];
#pragma unroll
  for (int nf = 0; nf < 4; ++nf) {
    int col = col0 + wn * 64 + nf * 16 + (lane & 15);
    b1[nf] = tb1[task * D_TOW + col];
    w2[nf] = tw2[task * D_TOW + col];
  }
  asm volatile("s_waitcnt vmcnt(0)" ::: "memory");  // clean FIFO before staging

  const int so_t = (((t & 7) ^ ((t >> 3) & 7)) << 4);
  const char* aBase = (const char*)sh + row0 * 2048 + (size_t)(t >> 3) * 2048 + so_t;
  const char* bRoot = (const char*)t1T + (size_t)task * (D_TOW * D_EXP * 2)
                      + (size_t)col0 * 2048 + (size_t)(t >> 3) * 2048 + so_t;
  char* sTB = (char*)&sT[0][0];

  auto SA = [&](int s, int hh, int kt) {
    const char* g = aBase + (size_t)hh * 262144 + (size_t)kt * 128;
    char* d = sTB + s * 65536 + hh * 16384 + t * 16;
    gll16(g, d); gll16(g + 131072, d + 8192);
    FENCE;
  };
  auto SB = [&](int s, int hh, int kt) {
    const char* g = bRoot + (size_t)hh * 262144 + (size_t)kt * 128;
    char* d = sTB + s * 65536 + 32768 + hh * 16384 + t * 16;
    gll16(g, d); gll16(g + 131072, d + 8192);
    FENCE;
  };

  __syncthreads();

  SA(0, 0, 0); SA(0, 1, 0); SB(0, 0, 0); SB(0, 1, 0);
  SA(1, 0, 1); SA(1, 1, 1); SB(1, 0, 1); SB(1, 1, 1);
  asm volatile("s_waitcnt vmcnt(8)" ::: "memory");
  __builtin_amdgcn_s_barrier();
  FENCE;

  f32x4 acc[8][4] = {};

  for (int kt = 0; kt < 16; ++kt) {
    const int cur = kt & 1;

    KTILE_COMPUTE(cur);

    FENCE;
    __builtin_amdgcn_s_barrier();
    FENCE;

    if (kt < 14) {
      SA(cur, 0, kt + 2); SA(cur, 1, kt + 2);
      SB(cur, 0, kt + 2); SB(cur, 1, kt + 2);
    }

    if (kt < 15) {
      if (kt < 14) { asm volatile("s_waitcnt vmcnt(8)" ::: "memory"); }
      else         { asm volatile("s_waitcnt vmcnt(0)" ::: "memory"); }
      __builtin_amdgcn_s_barrier();
      FENCE;
    }
  }

#pragma unroll
  for (int mf = 0; mf < 8; ++mf)
#pragma unroll
    for (int r = 0; r < 4; ++r) {
      float ssum = 0.f;
#pragma unroll
      for (int nf = 0; nf < 4; ++nf) {
        float v = acc[mf][nf][r] + b1[nf];
        v = v > 0.f ? v : 0.f;
        ssum += v * w2[nf];
      }
      ssum += __shfl_xor(ssum, 1);
      ssum += __shfl_xor(ssum, 2);
      ssum += __shfl_xor(ssum, 4);
      ssum += __shfl_xor(ssum, 8);
      if ((lane & 15) == 0) {
        long row = row0 + wm * 128 + mf * 16 + ((lane >> 4) << 2) + r;
        atomicAdd(&out[(size_t)task * B_DIM + row], ssum);
      }
    }
}

// ---------------- launch -----------------------------------------------------
extern "C" void kernel_launch(void* const* d_in, const int* in_sizes, int n_in,
                              void* d_out, int out_size, void* d_ws, size_t ws_size,
                              hipStream_t stream) {
  const float* x    = (const float*)d_in[0];
  const float* gw   = (const float*)d_in[1];
  const float* expw = (const float*)d_in[2];
  const float* expb = (const float*)d_in[3];
  const float* tw1  = (const float*)d_in[4];
  const float* tb1  = (const float*)d_in[5];
  const float* tw2  = (const float*)d_in[6];
  const float* tb2  = (const float*)d_in[7];
  float* out = (float*)d_out;

  char* ws = (char*)d_ws;
  _Float16* xh  = (_Float16*)ws;  ws += (size_t)B_DIM * D_IN * 2;          // 32 MB
  _Float16* ewT = (_Float16*)ws;  ws += (size_t)N_EXPT * D_IN * D_EXP * 2; // 16 MB
  _Float16* t1T = (_Float16*)ws;  ws += (size_t)N_TASK * D_TOW * D_EXP * 2; // 4 MB
  _Float16* shh = (_Float16*)ws;  ws += (size_t)B_DIM * D_EXP * 2;         // 32 MB
  float* gates  = (float*)ws;     ws += (size_t)B_DIM * N_EXPT * 4;        // 0.5 MB

  prep_x_kernel<<<B_DIM, 256, 0, stream>>>(x, gw, xh, gates);
  transpose_cvt_kernel<<<dim3(D_EXP / 64, D_IN / 64, N_EXPT), 256, 0, stream>>>(
      expw, ewT, D_IN, D_EXP);
  transpose_cvt_kernel<<<dim3(D_TOW / 64, D_EXP / 64, N_TASK), 256, 0, stream>>>(
      tw1, t1T, D_EXP, D_TOW);
  init_out_kernel<<<(N_TASK * B_DIM + 255) / 256, 256, 0, stream>>>(out, tb2);
  moe_expert_kernel<<<256, 512, 0, stream>>>(xh, ewT, expb, gates, shh);
  moe_tower_kernel<<<512, 512, 0, stream>>>(shh, t1T, tb1, tw2, out);
}

// Round 7
// 481.206 us; speedup vs baseline: 1.0665x; 1.0665x over previous
//
#include <hip/hip_runtime.h>
#include <hip/hip_bf16.h>

#define B_DIM   16384
#define D_IN    1024
#define D_EXP   1024
#define D_TOW   512
#define N_EXPT  8
#define N_TASK  4

typedef _Float16 f16x8 __attribute__((ext_vector_type(8)));
typedef _Float16 f16x4 __attribute__((ext_vector_type(4)));
typedef _Float16 f16x16h __attribute__((ext_vector_type(16)));
typedef float    f32x4 __attribute__((ext_vector_type(4)));
typedef float    f32x16 __attribute__((ext_vector_type(16)));

// ---------------- async global->LDS (16B per lane, wave-uniform LDS base) ---
__device__ __forceinline__ void gll16(const void* g, void* l) {
  __builtin_amdgcn_global_load_lds(
      (const __attribute__((address_space(1))) unsigned int*)g,
      (__attribute__((address_space(3))) unsigned int*)l,
      16, 0, 0);
}

// 32x32x16 fragment read from swizzled [rows][64] f16 LDS tile.
// Element (row, k): lane holds row=base+(lane&31), k = 16*s + 8*(lane>>5) + j.
// Global chunk gch = 2*s + (lane>>5); stored at LDS chunk gch ^ (row&7).
__device__ __forceinline__ f16x8 ldfrag32(const _Float16* sM, int rowbase, int s, int lane) {
  int rl = rowbase + (lane & 31);
  int ch = ((s << 1) + (lane >> 5)) ^ (rl & 7);
  return *(const f16x8*)&sM[rl * 64 + ch * 8];
}

// ---------------- prep: x -> f16, gates = x @ gate_w (fp32) ----------------
__global__ __launch_bounds__(256) void prep_x_kernel(
    const float* __restrict__ x, const float* __restrict__ gw,
    _Float16* __restrict__ xh, float* __restrict__ gates)
{
  __shared__ float sred[4][8];
  const int t = threadIdx.x;
  const long row = blockIdx.x;
  float4 v = ((const float4*)(x + row * D_IN))[t];
  f16x4 h;
  h[0] = (_Float16)v.x; h[1] = (_Float16)v.y; h[2] = (_Float16)v.z; h[3] = (_Float16)v.w;
  ((f16x4*)(xh + row * D_IN))[t] = h;

  float g[8];
#pragma unroll
  for (int e = 0; e < 8; ++e) g[e] = 0.f;
  const float* wp = gw + (size_t)t * 4 * 8;
  float xs[4] = {v.x, v.y, v.z, v.w};
#pragma unroll
  for (int j = 0; j < 4; ++j)
#pragma unroll
    for (int e = 0; e < 8; ++e) g[e] += xs[j] * wp[j * 8 + e];

#pragma unroll
  for (int e = 0; e < 8; ++e) {
    g[e] += __shfl_xor(g[e], 1);  g[e] += __shfl_xor(g[e], 2);
    g[e] += __shfl_xor(g[e], 4);  g[e] += __shfl_xor(g[e], 8);
    g[e] += __shfl_xor(g[e], 16); g[e] += __shfl_xor(g[e], 32);
  }
  if ((t & 63) == 0) {
#pragma unroll
    for (int e = 0; e < 8; ++e) sred[t >> 6][e] = g[e];
  }
  __syncthreads();
  if (t < 8) gates[row * 8 + t] = sred[0][t] + sred[1][t] + sred[2][t] + sred[3][t];
}

// ---------------- tiled transpose + fp32->f16: in[s][K][N] -> out[s][N][K] --
__global__ __launch_bounds__(256) void transpose_cvt_kernel(
    const float* __restrict__ in, _Float16* __restrict__ outp, int K, int N)
{
  __shared__ float tile[64][65];
  const int t = threadIdx.x;
  const int tx = t & 63, ty = t >> 6;
  const int n0 = blockIdx.x * 64;
  const int k0 = blockIdx.y * 64;
  const long s = blockIdx.z;
  const float* ip = in + s * (long)K * N;
  _Float16* op = outp + s * (long)K * N;
#pragma unroll
  for (int i = 0; i < 16; ++i) {
    int r = ty * 16 + i;
    tile[r][tx] = ip[(long)(k0 + r) * N + n0 + tx];
  }
  __syncthreads();
#pragma unroll
  for (int i = 0; i < 16; ++i) {
    int r = ty * 16 + i;
    op[(long)(n0 + r) * K + k0 + tx] = (_Float16)tile[tx][r];
  }
}

// ---------------- init d_out with tb2 --------------------------------------
__global__ void init_out_kernel(float* __restrict__ out, const float* __restrict__ tb2) {
  int i = blockIdx.x * 256 + threadIdx.x;
  if (i < N_TASK * B_DIM) out[i] = tb2[i >> 14];
}

// ============ r3 skeleton, 32x32x16 math ====================================
// BM=256, BN=128, BK=64; 8 waves (4M x 2N); per-wave C = 64x64 = 2x2 32-tiles.
// LDS slot (48KB): A [256x64]@0 (halves 8192 f16), B [128x64]@16384.
// Iteration = 2 K-tiles x 2 half-phases; 8 MFMA(32x32x16) per phase.
// Stage schedule + counted vmcnt identical to r3 (proven):
//   P0: s1.A (kt1)  P1: s0.B (kt0+2) | vmcnt(2)
//   P2: s0.A (kt0+2)  P3: s1.B (kt1+2) | vmcnt(2)
#define PHASE32(SLOT, H, STAGES, WAITS)                                        \
  do {                                                                         \
    const _Float16* sAq = &sT[SLOT][(wm >> 1) * 8192];                         \
    const _Float16* sBq = &sT[SLOT][16384 + wn * 4096];                        \
    f16x8 af[4];                                                               \
    _Pragma("unroll") for (int s = 0; s < 4; ++s)                              \
      af[s] = ldfrag32(sAq, (wm & 1) * 64 + (H) * 32, s, lane);                \
    if ((H) == 0) {                                                            \
      _Pragma("unroll") for (int nt = 0; nt < 2; ++nt)                         \
        _Pragma("unroll") for (int s = 0; s < 4; ++s)                          \
          bf[nt][s] = ldfrag32(sBq, nt * 32, s, lane);                         \
    }                                                                          \
    STAGES;                                                                    \
    asm volatile("" ::: "memory");                                             \
    __builtin_amdgcn_s_barrier();                                              \
    asm volatile("s_waitcnt lgkmcnt(0)" ::: "memory");                         \
    __builtin_amdgcn_sched_barrier(0);                                         \
    __builtin_amdgcn_s_setprio(1);                                             \
    _Pragma("unroll") for (int s = 0; s < 4; ++s)                              \
      _Pragma("unroll") for (int nt = 0; nt < 2; ++nt)                         \
        acc[H][nt] = __builtin_amdgcn_mfma_f32_32x32x16_f16(                   \
            af[s], bf[nt][s], acc[H][nt], 0, 0, 0);                            \
    __builtin_amdgcn_s_setprio(0);                                             \
    WAITS;                                                                     \
    asm volatile("" ::: "memory");                                             \
    __builtin_amdgcn_s_barrier();                                              \
  } while (0)

// ---------------- fused experts + gate-weighted combine ---------------------
// shared[b,d] = sum_e gates[b,e] * relu(x[b,:] @ exp_w[e,:,d] + exp_b[e,d])
__global__ __launch_bounds__(512, 2) void moe_expert_kernel(
    const _Float16* __restrict__ xh,    // [B,1024]
    const _Float16* __restrict__ ewT,   // [8][n=1024][k=1024]
    const float* __restrict__ expb,     // [8][1024]
    const float* __restrict__ gates,    // [B][8]
    _Float16* __restrict__ shout)       // [B,1024] f16
{
  __shared__ alignas(16) _Float16 sT[2][24576];   // per slot: A 32KB + B 16KB
  __shared__ float sG[256 * 8];
  __shared__ float sBias[8 * 128];
  const int t = threadIdx.x;
  const int lane = t & 63;
  const int wave = t >> 6;
  const int wm = wave >> 1, wn = wave & 1;
  const long row0 = (long)blockIdx.x * 256;
  const int col0 = blockIdx.y * 128;

  for (int i = t; i < 256 * 8; i += 512) sG[i] = gates[row0 * 8 + i];
  for (int i = t; i < 8 * 128; i += 512)
    sBias[i] = expb[(i >> 7) * D_EXP + col0 + (i & 127)];

  const int so_t = (((t & 7) ^ ((t >> 3) & 7)) << 4);
  const char* aBase = (const char*)xh + row0 * 2048 + (size_t)(t >> 3) * 2048 + so_t;
  const char* bRoot = (const char*)ewT + (size_t)col0 * 2048 + (size_t)(t >> 3) * 2048 + so_t;

  auto SA = [&](int s, int h, int step) {
    const char* g = aBase + (size_t)h * 262144 + (size_t)(step & 15) * 128;
    char* d = (char*)&sT[s][0] + h * 16384 + t * 16;
    gll16(g, d);
    gll16(g + 131072, d + 8192);
    asm volatile("" ::: "memory");
  };
  auto SB = [&](int s, int h, int step) {
    const char* g = bRoot + (size_t)(step >> 4) * 2097152 + (size_t)h * 131072
                    + (size_t)(step & 15) * 128;
    char* d = (char*)&sT[s][0] + 32768 + h * 8192 + t * 16;
    gll16(g, d);
    asm volatile("" ::: "memory");
  };

  __syncthreads();   // sG/sBias visible; vmcnt drained -> clean FIFO

  // prologue: s0.B, s0.A (kt0=0), s1.B (kt1=1); s1.A staged at P0 of iter 0
  SB(0, 0, 0); SB(0, 1, 0);
  SA(0, 0, 0); SA(0, 1, 0);
  SB(1, 0, 1); SB(1, 1, 1);
  asm volatile("s_waitcnt vmcnt(2)" ::: "memory");
  __builtin_amdgcn_s_barrier();

  f32x16 acc[2][2] = {};
  f16x16h shacc[2][2] = {};
  f16x8 bf[2][4];

  for (int it = 0; it < 64; ++it) {
    const int kt1 = 2 * it + 1;
    const bool pf = (it < 63);

    PHASE32(0, 0, { SA(1, 0, kt1); SA(1, 1, kt1); }, {});
    PHASE32(0, 1, { if (pf) { SB(0, 0, 2 * it + 2); SB(0, 1, 2 * it + 2); } },
          { if (pf) { asm volatile("s_waitcnt vmcnt(2)" ::: "memory"); }
            else    { asm volatile("s_waitcnt vmcnt(0)" ::: "memory"); } });
    PHASE32(1, 0, { if (pf) { SA(0, 0, 2 * it + 2); SA(0, 1, 2 * it + 2); } }, {});
    PHASE32(1, 1, { if (pf) { SB(1, 0, 2 * it + 3); SB(1, 1, 2 * it + 3); } },
          { if (pf) { asm volatile("s_waitcnt vmcnt(2)" ::: "memory"); } });

    if ((it & 7) == 7) {
      const int e = it >> 3;
#pragma unroll
      for (int mt = 0; mt < 2; ++mt)
#pragma unroll
        for (int nt = 0; nt < 2; ++nt) {
          float biasv = sBias[e * 128 + wn * 64 + nt * 32 + (lane & 31)];
          f16x16h shv = shacc[mt][nt];
#pragma unroll
          for (int reg = 0; reg < 16; ++reg) {
            int r = (reg & 3) + 8 * (reg >> 2) + 4 * (lane >> 5);
            int rowl = wm * 64 + mt * 32 + r;
            float gv = sG[rowl * 8 + e];
            float hv = acc[mt][nt][reg] + biasv;
            hv = hv > 0.f ? hv : 0.f;
            shv[reg] += (_Float16)(gv * hv);
            acc[mt][nt][reg] = 0.f;
          }
          shacc[mt][nt] = shv;
        }
    }
  }

  // write shared tile as f16
#pragma unroll
  for (int mt = 0; mt < 2; ++mt)
#pragma unroll
    for (int nt = 0; nt < 2; ++nt)
#pragma unroll
      for (int reg = 0; reg < 16; ++reg) {
        int r = (reg & 3) + 8 * (reg >> 2) + 4 * (lane >> 5);
        long row = row0 + wm * 64 + mt * 32 + r;
        shout[row * D_EXP + col0 + wn * 64 + nt * 32 + (lane & 31)] = shacc[mt][nt][reg];
      }
}

// ---------------- fused towers ----------------------------------------------
// out[task,b] += sum_h relu(shared[b,:] @ tw1[task,:,h] + tb1[task,h]) * tw2[task,h]
__global__ __launch_bounds__(512, 2) void moe_tower_kernel(
    const _Float16* __restrict__ sh,    // [B,1024] f16
    const _Float16* __restrict__ t1T,   // [4][h=512][d=1024] f16
    const float* __restrict__ tb1,      // [4][512]
    const float* __restrict__ tw2,      // [4][512]
    float* __restrict__ out)            // [4][B]
{
  __shared__ alignas(16) _Float16 sT[2][24576];
  const int t = threadIdx.x;
  const int lane = t & 63;
  const int wave = t >> 6;
  const int wm = wave >> 1, wn = wave & 1;
  const long row0 = (long)blockIdx.x * 256;
  const int task = blockIdx.y >> 2;
  const int col0 = (blockIdx.y & 3) * 128;

  float b1[2], w2[2];
#pragma unroll
  for (int nt = 0; nt < 2; ++nt) {
    int col = col0 + wn * 64 + nt * 32 + (lane & 31);
    b1[nt] = tb1[task * D_TOW + col];
    w2[nt] = tw2[task * D_TOW + col];
  }
  asm volatile("s_waitcnt vmcnt(0)" ::: "memory");  // clean FIFO before staging

  const int so_t = (((t & 7) ^ ((t >> 3) & 7)) << 4);
  const char* aBase = (const char*)sh + row0 * 2048 + (size_t)(t >> 3) * 2048 + so_t;
  const char* bRoot = (const char*)t1T + (size_t)task * (D_TOW * D_EXP * 2)
                      + (size_t)col0 * 2048 + (size_t)(t >> 3) * 2048 + so_t;

  auto SA = [&](int s, int h, int step) {
    const char* g = aBase + (size_t)h * 262144 + (size_t)step * 128;
    char* d = (char*)&sT[s][0] + h * 16384 + t * 16;
    gll16(g, d);
    gll16(g + 131072, d + 8192);
    asm volatile("" ::: "memory");
  };
  auto SB = [&](int s, int h, int step) {
    const char* g = bRoot + (size_t)h * 131072 + (size_t)step * 128;
    char* d = (char*)&sT[s][0] + 32768 + h * 8192 + t * 16;
    gll16(g, d);
    asm volatile("" ::: "memory");
  };

  __syncthreads();

  SB(0, 0, 0); SB(0, 1, 0);
  SA(0, 0, 0); SA(0, 1, 0);
  SB(1, 0, 1); SB(1, 1, 1);
  asm volatile("s_waitcnt vmcnt(2)" ::: "memory");
  __builtin_amdgcn_s_barrier();

  f32x16 acc[2][2] = {};
  f16x8 bf[2][4];

  for (int it = 0; it < 8; ++it) {
    const int kt1 = 2 * it + 1;
    const bool pf = (it < 7);

    PHASE32(0, 0, { SA(1, 0, kt1); SA(1, 1, kt1); }, {});
    PHASE32(0, 1, { if (pf) { SB(0, 0, 2 * it + 2); SB(0, 1, 2 * it + 2); } },
          { if (pf) { asm volatile("s_waitcnt vmcnt(2)" ::: "memory"); }
            else    { asm volatile("s_waitcnt vmcnt(0)" ::: "memory"); } });
    PHASE32(1, 0, { if (pf) { SA(0, 0, 2 * it + 2); SA(0, 1, 2 * it + 2); } }, {});
    PHASE32(1, 1, { if (pf) { SB(1, 0, 2 * it + 3); SB(1, 1, 2 * it + 3); } },
          { if (pf) { asm volatile("s_waitcnt vmcnt(2)" ::: "memory"); } });
  }

#pragma unroll
  for (int mt = 0; mt < 2; ++mt)
#pragma unroll
    for (int reg = 0; reg < 16; ++reg) {
      float ssum = 0.f;
#pragma unroll
      for (int nt = 0; nt < 2; ++nt) {
        float v = acc[mt][nt][reg] + b1[nt];
        v = v > 0.f ? v : 0.f;
        ssum += v * w2[nt];
      }
      ssum += __shfl_xor(ssum, 1);
      ssum += __shfl_xor(ssum, 2);
      ssum += __shfl_xor(ssum, 4);
      ssum += __shfl_xor(ssum, 8);
      ssum += __shfl_xor(ssum, 16);
      if ((lane & 31) == 0) {
        int r = (reg & 3) + 8 * (reg >> 2) + 4 * (lane >> 5);
        long row = row0 + wm * 64 + mt * 32 + r;
        atomicAdd(&out[(size_t)task * B_DIM + row], ssum);
      }
    }
}

// ---------------- launch -----------------------------------------------------
extern "C" void kernel_launch(void* const* d_in, const int* in_sizes, int n_in,
                              void* d_out, int out_size, void* d_ws, size_t ws_size,
                              hipStream_t stream) {
  const float* x    = (const float*)d_in[0];
  const float* gw   = (const float*)d_in[1];
  const float* expw = (const float*)d_in[2];
  const float* expb = (const float*)d_in[3];
  const float* tw1  = (const float*)d_in[4];
  const float* tb1  = (const float*)d_in[5];
  const float* tw2  = (const float*)d_in[6];
  const float* tb2  = (const float*)d_in[7];
  float* out = (float*)d_out;

  char* ws = (char*)d_ws;
  _Float16* xh  = (_Float16*)ws;  ws += (size_t)B_DIM * D_IN * 2;          // 32 MB
  _Float16* ewT = (_Float16*)ws;  ws += (size_t)N_EXPT * D_IN * D_EXP * 2; // 16 MB
  _Float16* t1T = (_Float16*)ws;  ws += (size_t)N_TASK * D_TOW * D_EXP * 2; // 4 MB
  _Float16* shh = (_Float16*)ws;  ws += (size_t)B_DIM * D_EXP * 2;         // 32 MB
  float* gates  = (float*)ws;     ws += (size_t)B_DIM * N_EXPT * 4;        // 0.5 MB

  prep_x_kernel<<<B_DIM, 256, 0, stream>>>(x, gw, xh, gates);
  transpose_cvt_kernel<<<dim3(D_EXP / 64, D_IN / 64, N_EXPT), 256, 0, stream>>>(
      expw, ewT, D_IN, D_EXP);
  transpose_cvt_kernel<<<dim3(D_TOW / 64, D_EXP / 64, N_TASK), 256, 0, stream>>>(
      tw1, t1T, D_EXP, D_TOW);
  init_out_kernel<<<(N_TASK * B_DIM + 255) / 256, 256, 0, stream>>>(out, tb2);
  moe_expert_kernel<<<dim3(B_DIM / 256, D_EXP / 128), 512, 0, stream>>>(
      xh, ewT, expb, gates, shh);
  moe_tower_kernel<<<dim3(B_DIM / 256, (N_TASK * D_TOW) / 128), 512, 0, stream>>>(
      shh, t1T, tb1, tw2, out);
}

// Round 8
// 438.742 us; speedup vs baseline: 1.1698x; 1.0968x over previous
//
#include <hip/hip_runtime.h>
#include <hip/hip_bf16.h>

#define B_DIM   16384
#define D_IN    1024
#define D_EXP   1024
#define D_TOW   512
#define N_EXPT  8
#define N_TASK  4

typedef _Float16 f16x8 __attribute__((ext_vector_type(8)));
typedef _Float16 f16x4 __attribute__((ext_vector_type(4)));
typedef float    f32x4 __attribute__((ext_vector_type(4)));

// ---------------- async global->LDS (16B per lane, wave-uniform LDS base) ---
__device__ __forceinline__ void gll16(const void* g, void* l) {
  __builtin_amdgcn_global_load_lds(
      (const __attribute__((address_space(1))) unsigned int*)g,
      (__attribute__((address_space(3))) unsigned int*)l,
      16, 0, 0);
}

// Fragment read from a swizzled [rows][64] f16 LDS tile (16x16x32 mapping).
// 16B chunk s within a 128B row holds global chunk s^(row&7).
__device__ __forceinline__ f16x8 ldfrag(const _Float16* sM, int rowbase, int ks, int lane) {
  int rl = rowbase + (lane & 15);
  int ch = ((ks << 2) + (lane >> 4)) ^ (rl & 7);
  return *(const f16x8*)&sM[rl * 64 + ch * 8];
}

// ---------------- prep: x -> f16, gates = x @ gate_w (fp32) ----------------
__global__ __launch_bounds__(256) void prep_x_kernel(
    const float* __restrict__ x, const float* __restrict__ gw,
    _Float16* __restrict__ xh, float* __restrict__ gates)
{
  __shared__ float sred[4][8];
  const int t = threadIdx.x;
  const long row = blockIdx.x;
  float4 v = ((const float4*)(x + row * D_IN))[t];
  f16x4 h;
  h[0] = (_Float16)v.x; h[1] = (_Float16)v.y; h[2] = (_Float16)v.z; h[3] = (_Float16)v.w;
  ((f16x4*)(xh + row * D_IN))[t] = h;

  float g[8];
#pragma unroll
  for (int e = 0; e < 8; ++e) g[e] = 0.f;
  const float* wp = gw + (size_t)t * 4 * 8;
  float xs[4] = {v.x, v.y, v.z, v.w};
#pragma unroll
  for (int j = 0; j < 4; ++j)
#pragma unroll
    for (int e = 0; e < 8; ++e) g[e] += xs[j] * wp[j * 8 + e];

#pragma unroll
  for (int e = 0; e < 8; ++e) {
    g[e] += __shfl_xor(g[e], 1);  g[e] += __shfl_xor(g[e], 2);
    g[e] += __shfl_xor(g[e], 4);  g[e] += __shfl_xor(g[e], 8);
    g[e] += __shfl_xor(g[e], 16); g[e] += __shfl_xor(g[e], 32);
  }
  if ((t & 63) == 0) {
#pragma unroll
    for (int e = 0; e < 8; ++e) sred[t >> 6][e] = g[e];
  }
  __syncthreads();
  if (t < 8) gates[row * 8 + t] = sred[0][t] + sred[1][t] + sred[2][t] + sred[3][t];
}

// ---------------- tiled transpose + fp32->f16: in[s][K][N] -> out[s][N][K] --
__global__ __launch_bounds__(256) void transpose_cvt_kernel(
    const float* __restrict__ in, _Float16* __restrict__ outp, int K, int N)
{
  __shared__ float tile[64][65];
  const int t = threadIdx.x;
  const int tx = t & 63, ty = t >> 6;
  const int n0 = blockIdx.x * 64;
  const int k0 = blockIdx.y * 64;
  const long s = blockIdx.z;
  const float* ip = in + s * (long)K * N;
  _Float16* op = outp + s * (long)K * N;
#pragma unroll
  for (int i = 0; i < 16; ++i) {
    int r = ty * 16 + i;
    tile[r][tx] = ip[(long)(k0 + r) * N + n0 + tx];
  }
  __syncthreads();
#pragma unroll
  for (int i = 0; i < 16; ++i) {
    int r = ty * 16 + i;
    op[(long)(n0 + r) * K + k0 + tx] = (_Float16)tile[tx][r];
  }
}

// ---------------- init d_out with tb2 --------------------------------------
__global__ void init_out_kernel(float* __restrict__ out, const float* __restrict__ tb2) {
  int i = blockIdx.x * 256 + threadIdx.x;
  if (i < N_TASK * B_DIM) out[i] = tb2[i >> 14];
}

// ============ r3 phase interior + 3-slot deep pipeline ======================
// BM=256, BN=128, BK=64; 8 waves (4M x 2N); per-wave C = 64x64.
// Slot (48KB): A [256x64]@0 (two 8192-f16 halves), B [128x64]@f16-ofs 16384.
// Tile t reads slot pA; stages tile t+2 into slot pC (>=4 phases of slack);
// vmcnt(6) once per tile retires exactly tile t+1's 6 loads.
#define PHASE3(PA, H, STAGES, WAITS)                                           \
  do {                                                                         \
    const _Float16* sAq = (const _Float16*)(PA) + (wm >> 1) * 8192;            \
    const _Float16* sBq = (const _Float16*)(PA) + 16384 + wn * 4096;           \
    f16x8 af[2][2];                                                            \
    _Pragma("unroll") for (int m2 = 0; m2 < 2; ++m2)                           \
      _Pragma("unroll") for (int ks = 0; ks < 2; ++ks)                         \
        af[m2][ks] = ldfrag(sAq, (wm & 1) * 64 + ((H) * 2 + m2) * 16, ks, lane);\
    if ((H) == 0) {                                                            \
      _Pragma("unroll") for (int nf = 0; nf < 4; ++nf)                         \
        _Pragma("unroll") for (int ks = 0; ks < 2; ++ks)                       \
          bf[nf][ks] = ldfrag(sBq, nf * 16, ks, lane);                         \
    }                                                                          \
    STAGES;                                                                    \
    asm volatile("" ::: "memory");                                             \
    __builtin_amdgcn_s_barrier();                                              \
    asm volatile("s_waitcnt lgkmcnt(0)" ::: "memory");                         \
    __builtin_amdgcn_sched_barrier(0);                                         \
    __builtin_amdgcn_s_setprio(1);                                             \
    _Pragma("unroll") for (int m2 = 0; m2 < 2; ++m2)                           \
      _Pragma("unroll") for (int nf = 0; nf < 4; ++nf)                         \
        _Pragma("unroll") for (int ks = 0; ks < 2; ++ks)                       \
          acc[(H) * 2 + m2][nf] = __builtin_amdgcn_mfma_f32_16x16x32_f16(      \
              af[m2][ks], bf[nf][ks], acc[(H) * 2 + m2][nf], 0, 0, 0);         \
    __builtin_amdgcn_s_setprio(0);                                             \
    WAITS;                                                                     \
    asm volatile("" ::: "memory");                                             \
    __builtin_amdgcn_s_barrier();                                              \
  } while (0)

// ---------------- fused experts + gate-weighted combine ---------------------
// shared[b,d] = sum_e gates[b,e] * relu(x[b,:] @ exp_w[e,:,d] + exp_b[e,d])
__global__ __launch_bounds__(512, 2) void moe_expert_kernel(
    const _Float16* __restrict__ xh,    // [B,1024]
    const _Float16* __restrict__ ewT,   // [8][n=1024][k=1024]
    const float* __restrict__ expb,     // [8][1024]
    const float* __restrict__ gates,    // [B][8]
    _Float16* __restrict__ shout)       // [B,1024] f16
{
  __shared__ alignas(16) _Float16 sT3[3][24576];  // 144KB: 3 slots (A32K+B16K)
  __shared__ float sG[256 * 8];                   // 8KB
  __shared__ _Float16 sBiasH[8 * 128];            // 2KB
  const int t = threadIdx.x;
  const int lane = t & 63;
  const int wave = t >> 6;
  const int wm = wave >> 1, wn = wave & 1;
  const long row0 = (long)blockIdx.x * 256;
  const int col0 = blockIdx.y * 128;

  for (int i = t; i < 256 * 8; i += 512) sG[i] = gates[row0 * 8 + i];
  for (int i = t; i < 8 * 128; i += 512)
    sBiasH[i] = (_Float16)expb[(i >> 7) * D_EXP + col0 + (i & 127)];

  const int so_t = (((t & 7) ^ ((t >> 3) & 7)) << 4);
  const char* aBase = (const char*)xh + row0 * 2048 + (size_t)(t >> 3) * 2048 + so_t;
  const char* bRoot = (const char*)ewT + (size_t)col0 * 2048 + (size_t)(t >> 3) * 2048 + so_t;

  auto SA = [&](char* pS, int h, int step) {     // A half h: 2 gll16
    const char* g = aBase + (size_t)h * 262144 + (size_t)(step & 15) * 128;
    char* d = pS + h * 16384 + t * 16;
    gll16(g, d);
    gll16(g + 131072, d + 8192);
    asm volatile("" ::: "memory");
  };
  auto SB = [&](char* pS, int h, int step) {     // B half h: 1 gll16
    const char* g = bRoot + (size_t)(step >> 4) * 2097152 + (size_t)h * 131072
                    + (size_t)(step & 15) * 128;
    char* d = pS + 32768 + h * 8192 + t * 16;
    gll16(g, d);
    asm volatile("" ::: "memory");
  };

  __syncthreads();   // sG/sBias visible; vmcnt fully drained -> clean FIFO

  char* pA = (char*)&sT3[0][0];
  char* pB = (char*)&sT3[1][0];
  char* pC = (char*)&sT3[2][0];

  // prologue: tile0 -> pA (6 loads), tile1 -> pB (6 loads)
  SA(pA, 0, 0); SB(pA, 0, 0); SA(pA, 1, 0); SB(pA, 1, 0);
  SA(pB, 0, 1); SB(pB, 0, 1); SA(pB, 1, 1); SB(pB, 1, 1);
  asm volatile("s_waitcnt vmcnt(6)" ::: "memory");   // tile0 landed
  __builtin_amdgcn_s_barrier();

  f32x4 acc[4][4] = {};
  f32x4 shacc[4][4] = {};
  f16x8 bf[4][2];

  for (int kt = 0; kt < 128; ++kt) {
    PHASE3(pA, 0, { if (kt < 126) { SA(pC, 0, kt + 2); SB(pC, 0, kt + 2); } }, {});
    PHASE3(pA, 1, { if (kt < 126) { SA(pC, 1, kt + 2); SB(pC, 1, kt + 2); } },
        { if (kt < 126)      { asm volatile("s_waitcnt vmcnt(6)" ::: "memory"); }
          else if (kt == 126){ asm volatile("s_waitcnt vmcnt(0)" ::: "memory"); } });

    if ((kt & 15) == 15) {          // expert boundary: relu+bias+gate combine
      const int e = kt >> 4;
      float bias4[4];
#pragma unroll
      for (int nf = 0; nf < 4; ++nf)
        bias4[nf] = (float)sBiasH[e * 128 + wn * 64 + nf * 16 + (lane & 15)];
#pragma unroll
      for (int mf = 0; mf < 4; ++mf) {
        int rbase = wm * 64 + mf * 16 + ((lane >> 4) << 2);
        float gv[4];
#pragma unroll
        for (int r = 0; r < 4; ++r) gv[r] = sG[(rbase + r) * 8 + e];
#pragma unroll
        for (int nf = 0; nf < 4; ++nf)
#pragma unroll
          for (int r = 0; r < 4; ++r) {
            float hv = acc[mf][nf][r] + bias4[nf];
            hv = hv > 0.f ? hv : 0.f;
            shacc[mf][nf][r] += gv[r] * hv;
            acc[mf][nf][r] = 0.f;
          }
      }
    }

    char* tmp = pA; pA = pB; pB = pC; pC = tmp;
  }

  // write shared tile as f16
#pragma unroll
  for (int mf = 0; mf < 4; ++mf)
#pragma unroll
    for (int r = 0; r < 4; ++r) {
      long row = row0 + wm * 64 + mf * 16 + ((lane >> 4) << 2) + r;
      _Float16* op = shout + row * D_EXP + col0 + wn * 64 + (lane & 15);
#pragma unroll
      for (int nf = 0; nf < 4; ++nf) op[nf * 16] = (_Float16)shacc[mf][nf][r];
    }
}

// ---------------- fused towers ----------------------------------------------
// out[task,b] += sum_h relu(shared[b,:] @ tw1[task,:,h] + tb1[task,h]) * tw2[task,h]
__global__ __launch_bounds__(512, 2) void moe_tower_kernel(
    const _Float16* __restrict__ sh,    // [B,1024] f16
    const _Float16* __restrict__ t1T,   // [4][h=512][d=1024] f16
    const float* __restrict__ tb1,      // [4][512]
    const float* __restrict__ tw2,      // [4][512]
    float* __restrict__ out)            // [4][B]
{
  __shared__ alignas(16) _Float16 sT3[3][24576];  // 144KB
  const int t = threadIdx.x;
  const int lane = t & 63;
  const int wave = t >> 6;
  const int wm = wave >> 1, wn = wave & 1;
  const long row0 = (long)blockIdx.x * 256;
  const int task = blockIdx.y >> 2;
  const int col0 = (blockIdx.y & 3) * 128;

  float b1[4], w2[4];
#pragma unroll
  for (int nf = 0; nf < 4; ++nf) {
    int col = col0 + wn * 64 + nf * 16 + (lane & 15);
    b1[nf] = tb1[task * D_TOW + col];
    w2[nf] = tw2[task * D_TOW + col];
  }
  asm volatile("s_waitcnt vmcnt(0)" ::: "memory");  // clean FIFO before staging

  const int so_t = (((t & 7) ^ ((t >> 3) & 7)) << 4);
  const char* aBase = (const char*)sh + row0 * 2048 + (size_t)(t >> 3) * 2048 + so_t;
  const char* bRoot = (const char*)t1T + (size_t)task * (D_TOW * D_EXP * 2)
                      + (size_t)col0 * 2048 + (size_t)(t >> 3) * 2048 + so_t;

  auto SA = [&](char* pS, int h, int step) {
    const char* g = aBase + (size_t)h * 262144 + (size_t)step * 128;
    char* d = pS + h * 16384 + t * 16;
    gll16(g, d);
    gll16(g + 131072, d + 8192);
    asm volatile("" ::: "memory");
  };
  auto SB = [&](char* pS, int h, int step) {
    const char* g = bRoot + (size_t)h * 131072 + (size_t)step * 128;
    char* d = pS + 32768 + h * 8192 + t * 16;
    gll16(g, d);
    asm volatile("" ::: "memory");
  };

  __syncthreads();

  char* pA = (char*)&sT3[0][0];
  char* pB = (char*)&sT3[1][0];
  char* pC = (char*)&sT3[2][0];

  SA(pA, 0, 0); SB(pA, 0, 0); SA(pA, 1, 0); SB(pA, 1, 0);
  SA(pB, 0, 1); SB(pB, 0, 1); SA(pB, 1, 1); SB(pB, 1, 1);
  asm volatile("s_waitcnt vmcnt(6)" ::: "memory");
  __builtin_amdgcn_s_barrier();

  f32x4 acc[4][4] = {};
  f16x8 bf[4][2];

  for (int kt = 0; kt < 16; ++kt) {
    PHASE3(pA, 0, { if (kt < 14) { SA(pC, 0, kt + 2); SB(pC, 0, kt + 2); } }, {});
    PHASE3(pA, 1, { if (kt < 14) { SA(pC, 1, kt + 2); SB(pC, 1, kt + 2); } },
        { if (kt < 14)       { asm volatile("s_waitcnt vmcnt(6)" ::: "memory"); }
          else if (kt == 14) { asm volatile("s_waitcnt vmcnt(0)" ::: "memory"); } });

    char* tmp = pA; pA = pB; pB = pC; pC = tmp;
  }

#pragma unroll
  for (int mf = 0; mf < 4; ++mf)
#pragma unroll
    for (int r = 0; r < 4; ++r) {
      float ssum = 0.f;
#pragma unroll
      for (int nf = 0; nf < 4; ++nf) {
        float v = acc[mf][nf][r] + b1[nf];
        v = v > 0.f ? v : 0.f;
        ssum += v * w2[nf];
      }
      ssum += __shfl_xor(ssum, 1);
      ssum += __shfl_xor(ssum, 2);
      ssum += __shfl_xor(ssum, 4);
      ssum += __shfl_xor(ssum, 8);
      if ((lane & 15) == 0) {
        long row = row0 + wm * 64 + mf * 16 + ((lane >> 4) << 2) + r;
        atomicAdd(&out[(size_t)task * B_DIM + row], ssum);
      }
    }
}

// ---------------- launch -----------------------------------------------------
extern "C" void kernel_launch(void* const* d_in, const int* in_sizes, int n_in,
                              void* d_out, int out_size, void* d_ws, size_t ws_size,
                              hipStream_t stream) {
  const float* x    = (const float*)d_in[0];
  const float* gw   = (const float*)d_in[1];
  const float* expw = (const float*)d_in[2];
  const float* expb = (const float*)d_in[3];
  const float* tw1  = (const float*)d_in[4];
  const float* tb1  = (const float*)d_in[5];
  const float* tw2  = (const float*)d_in[6];
  const float* tb2  = (const float*)d_in[7];
  float* out = (float*)d_out;

  char* ws = (char*)d_ws;
  _Float16* xh  = (_Float16*)ws;  ws += (size_t)B_DIM * D_IN * 2;          // 32 MB
  _Float16* ewT = (_Float16*)ws;  ws += (size_t)N_EXPT * D_IN * D_EXP * 2; // 16 MB
  _Float16* t1T = (_Float16*)ws;  ws += (size_t)N_TASK * D_TOW * D_EXP * 2; // 4 MB
  _Float16* shh = (_Float16*)ws;  ws += (size_t)B_DIM * D_EXP * 2;         // 32 MB
  float* gates  = (float*)ws;     ws += (size_t)B_DIM * N_EXPT * 4;        // 0.5 MB

  prep_x_kernel<<<B_DIM, 256, 0, stream>>>(x, gw, xh, gates);
  transpose_cvt_kernel<<<dim3(D_EXP / 64, D_IN / 64, N_EXPT), 256, 0, stream>>>(
      expw, ewT, D_IN, D_EXP);
  transpose_cvt_kernel<<<dim3(D_TOW / 64, D_EXP / 64, N_TASK), 256, 0, stream>>>(
      tw1, t1T, D_EXP, D_TOW);
  init_out_kernel<<<(N_TASK * B_DIM + 255) / 256, 256, 0, stream>>>(out, tb2);
  moe_expert_kernel<<<dim3(B_DIM / 256, D_EXP / 128), 512, 0, stream>>>(
      xh, ewT, expb, gates, shh);
  moe_tower_kernel<<<dim3(B_DIM / 256, (N_TASK * D_TOW) / 128), 512, 0, stream>>>(
      shh, t1T, tb1, tw2, out);
}

// Round 9
// 426.807 us; speedup vs baseline: 1.2025x; 1.0280x over previous
//
#include <hip/hip_runtime.h>
#include <hip/hip_bf16.h>

#define B_DIM   16384
#define D_IN    1024
#define D_EXP   1024
#define D_TOW   512
#define N_EXPT  8
#define N_TASK  4

typedef _Float16 f16x8 __attribute__((ext_vector_type(8)));
typedef _Float16 f16x4 __attribute__((ext_vector_type(4)));
typedef float    f32x4 __attribute__((ext_vector_type(4)));

// ---------------- async global->LDS (16B per lane, wave-uniform LDS base) ---
__device__ __forceinline__ void gll16(const void* g, void* l) {
  __builtin_amdgcn_global_load_lds(
      (const __attribute__((address_space(1))) unsigned int*)g,
      (__attribute__((address_space(3))) unsigned int*)l,
      16, 0, 0);
}

// Fragment read from a swizzled [rows][64] f16 LDS tile (16x16x32 mapping).
// 16B chunk s within a 128B row holds global chunk s^(row&7).
__device__ __forceinline__ f16x8 ldfrag(const _Float16* sM, int rowbase, int ks, int lane) {
  int rl = rowbase + (lane & 15);
  int ch = ((ks << 2) + (lane >> 4)) ^ (rl & 7);
  return *(const f16x8*)&sM[rl * 64 + ch * 8];
}

#define FENCE asm volatile("" ::: "memory")

// ---------------- prep: x -> f16, gates = x @ gate_w (fp32) ----------------
__global__ __launch_bounds__(256) void prep_x_kernel(
    const float* __restrict__ x, const float* __restrict__ gw,
    _Float16* __restrict__ xh, float* __restrict__ gates)
{
  __shared__ float sred[4][8];
  const int t = threadIdx.x;
  const long row = blockIdx.x;
  float4 v = ((const float4*)(x + row * D_IN))[t];
  f16x4 h;
  h[0] = (_Float16)v.x; h[1] = (_Float16)v.y; h[2] = (_Float16)v.z; h[3] = (_Float16)v.w;
  ((f16x4*)(xh + row * D_IN))[t] = h;

  float g[8];
#pragma unroll
  for (int e = 0; e < 8; ++e) g[e] = 0.f;
  const float* wp = gw + (size_t)t * 4 * 8;
  float xs[4] = {v.x, v.y, v.z, v.w};
#pragma unroll
  for (int j = 0; j < 4; ++j)
#pragma unroll
    for (int e = 0; e < 8; ++e) g[e] += xs[j] * wp[j * 8 + e];

#pragma unroll
  for (int e = 0; e < 8; ++e) {
    g[e] += __shfl_xor(g[e], 1);  g[e] += __shfl_xor(g[e], 2);
    g[e] += __shfl_xor(g[e], 4);  g[e] += __shfl_xor(g[e], 8);
    g[e] += __shfl_xor(g[e], 16); g[e] += __shfl_xor(g[e], 32);
  }
  if ((t & 63) == 0) {
#pragma unroll
    for (int e = 0; e < 8; ++e) sred[t >> 6][e] = g[e];
  }
  __syncthreads();
  if (t < 8) gates[row * 8 + t] = sred[0][t] + sred[1][t] + sred[2][t] + sred[3][t];
}

// ---------------- tiled transpose + fp32->f16: in[s][K][N] -> out[s][N][K] --
__global__ __launch_bounds__(256) void transpose_cvt_kernel(
    const float* __restrict__ in, _Float16* __restrict__ outp, int K, int N)
{
  __shared__ float tile[64][65];
  const int t = threadIdx.x;
  const int tx = t & 63, ty = t >> 6;
  const int n0 = blockIdx.x * 64;
  const int k0 = blockIdx.y * 64;
  const long s = blockIdx.z;
  const float* ip = in + s * (long)K * N;
  _Float16* op = outp + s * (long)K * N;
#pragma unroll
  for (int i = 0; i < 16; ++i) {
    int r = ty * 16 + i;
    tile[r][tx] = ip[(long)(k0 + r) * N + n0 + tx];
  }
  __syncthreads();
#pragma unroll
  for (int i = 0; i < 16; ++i) {
    int r = ty * 16 + i;
    op[(long)(n0 + r) * K + k0 + tx] = (_Float16)tile[tx][r];
  }
}

// ---------------- init d_out with tb2 --------------------------------------
__global__ void init_out_kernel(float* __restrict__ out, const float* __restrict__ tb2) {
  int i = blockIdx.x * 256 + threadIdx.x;
  if (i < N_TASK * B_DIM) out[i] = tb2[i >> 14];
}

// ============ ks-split, register-double-buffered pipeline ===================
// BM=256, BN=128, BK=64; 8 waves (4M x 2N); per-wave C = 64x64.
// Slot (48KB): A [256x64], B [128x64] at f16 offset 16384. 3 slots.
// Phase = one ks slice: {16 MFMA on preloaded regs | 8 ds_reads next slice |
// 3 gll16 stage} -> vmcnt(3) -> barrier. 2 phases (=2 barriers) per K-tile.
// Stage distance 2 tiles; vmcnt(3) retires prev phase's stages (FIFO-checked).

#define LD_FRAGS(AF, BF, SLOT, KS)                                             \
    _Pragma("unroll") for (int mf = 0; mf < 4; ++mf)                           \
      AF[mf] = ldfrag(&sT3[SLOT][(wm >> 1) * 8192], (wm & 1) * 64 + mf * 16,   \
                      (KS), lane);                                             \
    _Pragma("unroll") for (int nf = 0; nf < 4; ++nf)                           \
      BF[nf] = ldfrag(&sT3[SLOT][16384 + wn * 4096], nf * 16, (KS), lane)

#define MFMA16(AF, BF)                                                         \
    _Pragma("unroll") for (int mf = 0; mf < 4; ++mf)                           \
      _Pragma("unroll") for (int nf = 0; nf < 4; ++nf)                         \
        acc[mf][nf] = __builtin_amdgcn_mfma_f32_16x16x32_f16(                  \
            AF[mf], BF[nf], acc[mf][nf], 0, 0, 0)

// one K-tile; SC = cur slot (this tile), SN = next slot, SS = stage slot
#define TILE_BODY(SC, SN, SS, KT, NT, EPI)                                     \
  do {                                                                         \
    const int kt_ = (KT);                                                      \
    /* phase A: MFMA ks0 (af0/bf0), load ks1 frags, stage h0 of tile+2 */      \
    if (kt_ < (NT)-2) { SAg(SS, 0, kt_ + 2); SBg(SS, 0, kt_ + 2); }            \
    LD_FRAGS(af1, bf1, SC, 1);                                                 \
    MFMA16(af0, bf0);                                                          \
    FENCE;                                                                     \
    if (kt_ < (NT)-2) { asm volatile("s_waitcnt vmcnt(3)" ::: "memory"); }     \
    else              { asm volatile("s_waitcnt vmcnt(0)" ::: "memory"); }     \
    __builtin_amdgcn_s_barrier();                                              \
    /* phase B: MFMA ks1, load ks0 of next tile, stage h1 of tile+2 */         \
    if (kt_ < (NT)-2) { SAg(SS, 1, kt_ + 2); SBg(SS, 1, kt_ + 2); }            \
    if (kt_ < (NT)-1) { LD_FRAGS(af0, bf0, SN, 0); }                           \
    MFMA16(af1, bf1);                                                          \
    FENCE;                                                                     \
    if (kt_ < (NT)-2) { asm volatile("s_waitcnt vmcnt(3)" ::: "memory"); }     \
    else              { asm volatile("s_waitcnt vmcnt(0)" ::: "memory"); }     \
    __builtin_amdgcn_s_barrier();                                              \
    EPI;                                                                       \
  } while (0)

// ---------------- fused experts + gate-weighted combine ---------------------
// shared[b,d] = sum_e gates[b,e] * relu(x[b,:] @ exp_w[e,:,d] + exp_b[e,d])
__global__ __launch_bounds__(512, 2) void moe_expert_kernel(
    const _Float16* __restrict__ xh,    // [B,1024]
    const _Float16* __restrict__ ewT,   // [8][n=1024][k=1024]
    const float* __restrict__ expb,     // [8][1024]
    const float* __restrict__ gates,    // [B][8]
    _Float16* __restrict__ shout)       // [B,1024] f16
{
  __shared__ alignas(16) _Float16 sT3[3][24576];  // 144KB
  __shared__ float sG[256 * 8];                   // 8KB
  __shared__ _Float16 sBiasH[8 * 128];            // 2KB
  const int t = threadIdx.x;
  const int lane = t & 63;
  const int wave = t >> 6;
  const int wm = wave >> 1, wn = wave & 1;
  const long row0 = (long)blockIdx.x * 256;
  const int col0 = blockIdx.y * 128;

  for (int i = t; i < 256 * 8; i += 512) sG[i] = gates[row0 * 8 + i];
  for (int i = t; i < 8 * 128; i += 512)
    sBiasH[i] = (_Float16)expb[(i >> 7) * D_EXP + col0 + (i & 127)];

  const int so_t = (((t & 7) ^ ((t >> 3) & 7)) << 4);
  const char* aBase = (const char*)xh + row0 * 2048 + (size_t)(t >> 3) * 2048 + so_t;
  const char* bRoot = (const char*)ewT + (size_t)col0 * 2048 + (size_t)(t >> 3) * 2048 + so_t;

  // stage A half h (2 loads) / B half h (1 load) of K-tile `step` into slot S
  auto SAg = [&](int S, int h, int step) {
    const char* g = aBase + (size_t)h * 262144 + (size_t)(step & 15) * 128;
    char* d = (char*)&sT3[S][0] + h * 16384 + t * 16;
    gll16(g, d);
    gll16(g + 131072, d + 8192);
    FENCE;
  };
  auto SBg = [&](int S, int h, int step) {
    const char* g = bRoot + (size_t)(step >> 4) * 2097152 + (size_t)h * 131072
                    + (size_t)(step & 15) * 128;
    char* d = (char*)&sT3[S][0] + 32768 + h * 8192 + t * 16;
    gll16(g, d);
    FENCE;
  };

  __syncthreads();   // sG/sBias visible; vmcnt fully drained

  // prologue: tile0 -> slot0, tile1 -> slot1, drain, preload ks0(0) frags
  SAg(0, 0, 0); SBg(0, 0, 0); SAg(0, 1, 0); SBg(0, 1, 0);
  SAg(1, 0, 1); SBg(1, 0, 1); SAg(1, 1, 1); SBg(1, 1, 1);
  asm volatile("s_waitcnt vmcnt(0)" ::: "memory");
  __builtin_amdgcn_s_barrier();

  f32x4 acc[4][4] = {};
  f16x4 shacc[4][4] = {};
  f16x8 af0[4], bf0[4], af1[4], bf1[4];
  LD_FRAGS(af0, bf0, 0, 0);

#define EPI_E(KT)                                                              \
    if (((KT) & 15) == 15) {                                                   \
      const int e = (KT) >> 4;                                                 \
      float bias4[4];                                                          \
      _Pragma("unroll") for (int nf = 0; nf < 4; ++nf)                         \
        bias4[nf] = (float)sBiasH[e * 128 + wn * 64 + nf * 16 + (lane & 15)];  \
      _Pragma("unroll") for (int mf = 0; mf < 4; ++mf) {                       \
        int rbase = wm * 64 + mf * 16 + ((lane >> 4) << 2);                    \
        float gv[4];                                                           \
        _Pragma("unroll") for (int r = 0; r < 4; ++r)                          \
          gv[r] = sG[(rbase + r) * 8 + e];                                     \
        _Pragma("unroll") for (int nf = 0; nf < 4; ++nf) {                     \
          f16x4 sh = shacc[mf][nf];                                            \
          _Pragma("unroll") for (int r = 0; r < 4; ++r) {                      \
            float hv = acc[mf][nf][r] + bias4[nf];                             \
            hv = hv > 0.f ? hv : 0.f;                                          \
            sh[r] += (_Float16)(gv[r] * hv);                                   \
            acc[mf][nf][r] = 0.f;                                              \
          }                                                                    \
          shacc[mf][nf] = sh;                                                  \
        }                                                                      \
      }                                                                        \
    }

  // 128 K-tiles, unrolled by 3 so slot indices are compile-time
  for (int base = 0; base < 126; base += 3) {
    TILE_BODY(0, 1, 2, base + 0, 128, EPI_E(base + 0));
    TILE_BODY(1, 2, 0, base + 1, 128, EPI_E(base + 1));
    TILE_BODY(2, 0, 1, base + 2, 128, EPI_E(base + 2));
  }
  TILE_BODY(0, 1, 2, 126, 128, EPI_E(126));
  TILE_BODY(1, 2, 0, 127, 128, EPI_E(127));
#undef EPI_E

  // write shared tile as f16
#pragma unroll
  for (int mf = 0; mf < 4; ++mf)
#pragma unroll
    for (int r = 0; r < 4; ++r) {
      long row = row0 + wm * 64 + mf * 16 + ((lane >> 4) << 2) + r;
      _Float16* op = shout + row * D_EXP + col0 + wn * 64 + (lane & 15);
#pragma unroll
      for (int nf = 0; nf < 4; ++nf) op[nf * 16] = shacc[mf][nf][r];
    }
}

// ---------------- fused towers ----------------------------------------------
// out[task,b] += sum_h relu(shared[b,:] @ tw1[task,:,h] + tb1[task,h]) * tw2[task,h]
__global__ __launch_bounds__(512, 2) void moe_tower_kernel(
    const _Float16* __restrict__ sh,    // [B,1024] f16
    const _Float16* __restrict__ t1T,   // [4][h=512][d=1024] f16
    const float* __restrict__ tb1,      // [4][512]
    const float* __restrict__ tw2,      // [4][512]
    float* __restrict__ out)            // [4][B]
{
  __shared__ alignas(16) _Float16 sT3[3][24576];  // 144KB
  const int t = threadIdx.x;
  const int lane = t & 63;
  const int wave = t >> 6;
  const int wm = wave >> 1, wn = wave & 1;
  const long row0 = (long)blockIdx.x * 256;
  const int task = blockIdx.y >> 2;
  const int col0 = (blockIdx.y & 3) * 128;

  float b1[4], w2[4];
#pragma unroll
  for (int nf = 0; nf < 4; ++nf) {
    int col = col0 + wn * 64 + nf * 16 + (lane & 15);
    b1[nf] = tb1[task * D_TOW + col];
    w2[nf] = tw2[task * D_TOW + col];
  }
  asm volatile("s_waitcnt vmcnt(0)" ::: "memory");  // clean FIFO

  const int so_t = (((t & 7) ^ ((t >> 3) & 7)) << 4);
  const char* aBase = (const char*)sh + row0 * 2048 + (size_t)(t >> 3) * 2048 + so_t;
  const char* bRoot = (const char*)t1T + (size_t)task * (D_TOW * D_EXP * 2)
                      + (size_t)col0 * 2048 + (size_t)(t >> 3) * 2048 + so_t;

  auto SAg = [&](int S, int h, int step) {
    const char* g = aBase + (size_t)h * 262144 + (size_t)step * 128;
    char* d = (char*)&sT3[S][0] + h * 16384 + t * 16;
    gll16(g, d);
    gll16(g + 131072, d + 8192);
    FENCE;
  };
  auto SBg = [&](int S, int h, int step) {
    const char* g = bRoot + (size_t)h * 131072 + (size_t)step * 128;
    char* d = (char*)&sT3[S][0] + 32768 + h * 8192 + t * 16;
    gll16(g, d);
    FENCE;
  };

  __syncthreads();

  SAg(0, 0, 0); SBg(0, 0, 0); SAg(0, 1, 0); SBg(0, 1, 0);
  SAg(1, 0, 1); SBg(1, 0, 1); SAg(1, 1, 1); SBg(1, 1, 1);
  asm volatile("s_waitcnt vmcnt(0)" ::: "memory");
  __builtin_amdgcn_s_barrier();

  f32x4 acc[4][4] = {};
  f16x8 af0[4], bf0[4], af1[4], bf1[4];
  LD_FRAGS(af0, bf0, 0, 0);

  // 16 K-tiles: 5 groups of 3 + tile 15 (slot 0)
  for (int base = 0; base < 15; base += 3) {
    TILE_BODY(0, 1, 2, base + 0, 16, );
    TILE_BODY(1, 2, 0, base + 1, 16, );
    TILE_BODY(2, 0, 1, base + 2, 16, );
  }
  TILE_BODY(0, 1, 2, 15, 16, );

#pragma unroll
  for (int mf = 0; mf < 4; ++mf)
#pragma unroll
    for (int r = 0; r < 4; ++r) {
      float ssum = 0.f;
#pragma unroll
      for (int nf = 0; nf < 4; ++nf) {
        float v = acc[mf][nf][r] + b1[nf];
        v = v > 0.f ? v : 0.f;
        ssum += v * w2[nf];
      }
      ssum += __shfl_xor(ssum, 1);
      ssum += __shfl_xor(ssum, 2);
      ssum += __shfl_xor(ssum, 4);
      ssum += __shfl_xor(ssum, 8);
      if ((lane & 15) == 0) {
        long row = row0 + wm * 64 + mf * 16 + ((lane >> 4) << 2) + r;
        atomicAdd(&out[(size_t)task * B_DIM + row], ssum);
      }
    }
}

// ---------------- launch -----------------------------------------------------
extern "C" void kernel_launch(void* const* d_in, const int* in_sizes, int n_in,
                              void* d_out, int out_size, void* d_ws, size_t ws_size,
                              hipStream_t stream) {
  const float* x    = (const float*)d_in[0];
  const float* gw   = (const float*)d_in[1];
  const float* expw = (const float*)d_in[2];
  const float* expb = (const float*)d_in[3];
  const float* tw1  = (const float*)d_in[4];
  const float* tb1  = (const float*)d_in[5];
  const float* tw2  = (const float*)d_in[6];
  const float* tb2  = (const float*)d_in[7];
  float* out = (float*)d_out;

  char* ws = (char*)d_ws;
  _Float16* xh  = (_Float16*)ws;  ws += (size_t)B_DIM * D_IN * 2;          // 32 MB
  _Float16* ewT = (_Float16*)ws;  ws += (size_t)N_EXPT * D_IN * D_EXP * 2; // 16 MB
  _Float16* t1T = (_Float16*)ws;  ws += (size_t)N_TASK * D_TOW * D_EXP * 2; // 4 MB
  _Float16* shh = (_Float16*)ws;  ws += (size_t)B_DIM * D_EXP * 2;         // 32 MB
  float* gates  = (float*)ws;     ws += (size_t)B_DIM * N_EXPT * 4;        // 0.5 MB

  prep_x_kernel<<<B_DIM, 256, 0, stream>>>(x, gw, xh, gates);
  transpose_cvt_kernel<<<dim3(D_EXP / 64, D_IN / 64, N_EXPT), 256, 0, stream>>>(
      expw, ewT, D_IN, D_EXP);
  transpose_cvt_kernel<<<dim3(D_TOW / 64, D_EXP / 64, N_TASK), 256, 0, stream>>>(
      tw1, t1T, D_EXP, D_TOW);
  init_out_kernel<<<(N_TASK * B_DIM + 255) / 256, 256, 0, stream>>>(out, tb2);
  moe_expert_kernel<<<dim3(B_DIM / 256, D_EXP / 128), 512, 0, stream>>>(
      xh, ewT, expb, gates, shh);
  moe_tower_kernel<<<dim3(B_DIM / 256, (N_TASK * D_TOW) / 128), 512, 0, stream>>>(
      shh, t1T, tb1, tw2, out);
}